// Round 1
// baseline (309.810 us; speedup 1.0000x reference)
//
#include <hip/hip_runtime.h>
#include <hip/hip_bf16.h>

#define T_LEN 1024
#define D_DIM 64
#define BATCH 32

// ---------------------------------------------------------------------------
// Kernel 1: pairwise Euclidean distance matrix, GEMM-trick, 64x64 tiles.
// grid (16, 16, batches_in_group), block 256. Writes cost[b][i][j] fp32.
// ---------------------------------------------------------------------------
__global__ __launch_bounds__(256) void cost_kernel(const float* __restrict__ pred,
                                                   const float* __restrict__ targ,
                                                   float* __restrict__ cost) {
    const int b = blockIdx.z;
    const float* P = pred + (size_t)b * T_LEN * D_DIM;
    const float* T = targ + (size_t)b * T_LEN * D_DIM;
    float* C = cost + (size_t)b * T_LEN * T_LEN;
    const int row0 = blockIdx.y * 64;
    const int col0 = blockIdx.x * 64;

    // K-major LDS tiles, padded stride 68 (16B-aligned rows, conflict-light)
    __shared__ __align__(16) float ps[64][68];  // ps[k][r] = pred[row0+r][k]
    __shared__ __align__(16) float ts[64][68];  // ts[k][c] = targ[col0+c][k]
    __shared__ float p2[64], t2[64];

    const int tid = threadIdx.x;

    // Stage 64 rows x 64 k of each input (coalesced float4 global loads).
#pragma unroll
    for (int it = 0; it < 4; it++) {
        int f = tid + 256 * it;        // 0..1023
        int row = f >> 4;              // 0..63
        int kc = f & 15;               // 0..15 (float4 chunk)
        float4 v = *(const float4*)(P + (size_t)(row0 + row) * D_DIM + 4 * kc);
        ps[4 * kc + 0][row] = v.x; ps[4 * kc + 1][row] = v.y;
        ps[4 * kc + 2][row] = v.z; ps[4 * kc + 3][row] = v.w;
        float4 w = *(const float4*)(T + (size_t)(col0 + row) * D_DIM + 4 * kc);
        ts[4 * kc + 0][row] = w.x; ts[4 * kc + 1][row] = w.y;
        ts[4 * kc + 2][row] = w.z; ts[4 * kc + 3][row] = w.w;
    }
    __syncthreads();

    // Squared norms for the tile rows/cols.
    if (tid < 128) {
        int idx = tid & 63;
        float s = 0.0f;
        if (tid < 64) {
#pragma unroll
            for (int k = 0; k < 64; k++) { float x = ps[k][idx]; s += x * x; }
            p2[idx] = s;
        } else {
#pragma unroll
            for (int k = 0; k < 64; k++) { float x = ts[k][idx]; s += x * x; }
            t2[idx] = s;
        }
    }
    __syncthreads();

    // 4x4 micro-tile per thread.
    const int tx = tid & 15, ty = tid >> 4;
    const int r0 = 4 * ty, c0 = 4 * tx;
    float acc[4][4];
#pragma unroll
    for (int i = 0; i < 4; i++)
#pragma unroll
        for (int j = 0; j < 4; j++) acc[i][j] = 0.0f;

#pragma unroll 8
    for (int k = 0; k < 64; k++) {
        float4 a = *(const float4*)&ps[k][r0];
        float4 bb = *(const float4*)&ts[k][c0];
        float av[4] = {a.x, a.y, a.z, a.w};
        float bv[4] = {bb.x, bb.y, bb.z, bb.w};
#pragma unroll
        for (int i = 0; i < 4; i++)
#pragma unroll
            for (int j = 0; j < 4; j++) acc[i][j] += av[i] * bv[j];
    }

#pragma unroll
    for (int i = 0; i < 4; i++) {
        float4 o;
        float pa = p2[r0 + i];
        float d0 = pa + t2[c0 + 0] - 2.0f * acc[i][0];
        float d1 = pa + t2[c0 + 1] - 2.0f * acc[i][1];
        float d2 = pa + t2[c0 + 2] - 2.0f * acc[i][2];
        float d3 = pa + t2[c0 + 3] - 2.0f * acc[i][3];
        o.x = sqrtf(fmaxf(d0, 1e-12f));
        o.y = sqrtf(fmaxf(d1, 1e-12f));
        o.z = sqrtf(fmaxf(d2, 1e-12f));
        o.w = sqrtf(fmaxf(d3, 1e-12f));
        *(float4*)(C + (size_t)(row0 + r0 + i) * T_LEN + (col0 + c0)) = o;
    }
}

// ---------------------------------------------------------------------------
// Kernel 2: Frechet DP, one wave per batch. Lane t owns columns [16t,16t+16).
// Time-skewed pipeline: at step s, lane t computes row r = s - t, receiving
// the left/diag boundary from lane t-1 via shfl_up. No barriers, no LDS.
// Cost rows prefetched PD steps ahead into registers.
// ---------------------------------------------------------------------------
#define PD 8
__global__ __launch_bounds__(64) void dp_kernel(const float* __restrict__ cost,
                                                float* __restrict__ out) {
    const int b = blockIdx.x;
    const int t = threadIdx.x;  // lane 0..63
    const float INF = __builtin_inff();
    const float* C = cost + (size_t)b * T_LEN * T_LEN + 16 * t;

    float prev[16];
#pragma unroll
    for (int j = 0; j < 16; j++) prev[j] = INF;
    float right_out = INF;
    float diag_feed = INF;

    float4 pipe[PD][4];
#pragma unroll
    for (int d = 0; d < PD; d++) {
        int r = d - t; r = r < 0 ? 0 : (r > T_LEN - 1 ? T_LEN - 1 : r);
        const float4* p = (const float4*)(C + (size_t)r * T_LEN);
        pipe[d][0] = p[0]; pipe[d][1] = p[1]; pipe[d][2] = p[2]; pipe[d][3] = p[3];
    }

    const int S = T_LEN + 63;                    // 1087 steps
    const int NCH = (S + PD - 1) / PD;           // chunks (pad harmless)
    int s = 0;
    for (int chunk = 0; chunk < NCH; chunk++) {
#pragma unroll
        for (int u = 0; u < PD; u++, s++) {
            int r = s - t;
            float inc = __shfl_up(right_out, 1, 64);
            float left = inc, diag = diag_feed;
            diag_feed = inc;
            if (t == 0) { left = (r == 0) ? -INF : INF; diag = INF; }
            if (r >= 0 && r < T_LEN) {
                const float* cb = (const float*)&pipe[u][0];
#pragma unroll
                for (int j = 0; j < 16; j++) {
                    float c = cb[j];
                    float up = prev[j];
                    float v = fmaxf(c, fminf(fminf(up, diag), left));
                    diag = up; left = v; prev[j] = v;
                }
                right_out = left;
            }
            // prefetch row for step s+PD (clamped address, data unused if OOB)
            int rn = s + PD - t; rn = rn < 0 ? 0 : (rn > T_LEN - 1 ? T_LEN - 1 : rn);
            const float4* p = (const float4*)(C + (size_t)rn * T_LEN);
            pipe[u][0] = p[0]; pipe[u][1] = p[1]; pipe[u][2] = p[2]; pipe[u][3] = p[3];
        }
    }
    if (t == 63) atomicAdd(out, prev[15] * (1.0f / (float)BATCH));
}

// ---------------------------------------------------------------------------
// Fallback: fused DP computing distances on the fly (used only if ws_size
// can't hold even one 4 MB cost matrix). Same skewed-pipeline structure.
// ---------------------------------------------------------------------------
__global__ __launch_bounds__(64) void dp_fused_kernel(const float* __restrict__ pred,
                                                      const float* __restrict__ targ,
                                                      float* __restrict__ out) {
    const int b = blockIdx.x;
    const int t = threadIdx.x;
    const float INF = __builtin_inff();
    const float* P = pred + (size_t)b * T_LEN * D_DIM;
    const float* T = targ + (size_t)b * T_LEN * D_DIM + (size_t)(16 * t) * D_DIM;

    float prev[16];
#pragma unroll
    for (int j = 0; j < 16; j++) prev[j] = INF;
    float right_out = INF;
    float diag_feed = INF;

    for (int s = 0; s < T_LEN + 63; s++) {
        int r = s - t;
        float inc = __shfl_up(right_out, 1, 64);
        float left = inc, diag = diag_feed;
        diag_feed = inc;
        if (t == 0) { left = (r == 0) ? -INF : INF; diag = INF; }
        if (r >= 0 && r < T_LEN) {
            float4 pr[16];
            const float4* pp = (const float4*)(P + (size_t)r * D_DIM);
#pragma unroll
            for (int q = 0; q < 16; q++) pr[q] = pp[q];
#pragma unroll
            for (int j = 0; j < 16; j++) {
                const float4* tp = (const float4*)(T + (size_t)j * D_DIM);
                float acc = 0.0f;
#pragma unroll
                for (int q = 0; q < 16; q++) {
                    float4 tv = tp[q];
                    float dx = pr[q].x - tv.x; acc += dx * dx;
                    float dy = pr[q].y - tv.y; acc += dy * dy;
                    float dz = pr[q].z - tv.z; acc += dz * dz;
                    float dw = pr[q].w - tv.w; acc += dw * dw;
                }
                float c = sqrtf(fmaxf(acc, 1e-12f));
                float up = prev[j];
                float v = fmaxf(c, fminf(fminf(up, diag), left));
                diag = up; left = v; prev[j] = v;
            }
            right_out = left;
        }
    }
    if (t == 63) atomicAdd(out, prev[15] * (1.0f / (float)BATCH));
}

extern "C" void kernel_launch(void* const* d_in, const int* in_sizes, int n_in,
                              void* d_out, int out_size, void* d_ws, size_t ws_size,
                              hipStream_t stream) {
    const float* pred = (const float*)d_in[0];
    const float* targ = (const float*)d_in[1];
    float* out = (float*)d_out;

    hipMemsetAsync(out, 0, sizeof(float) * out_size, stream);

    const size_t per_batch = (size_t)T_LEN * T_LEN * sizeof(float);  // 4 MB
    int bpg = (int)(ws_size / per_batch);
    if (bpg > BATCH) bpg = BATCH;

    if (bpg >= 1) {
        float* cost = (float*)d_ws;
        for (int g0 = 0; g0 < BATCH; g0 += bpg) {
            int gb = (BATCH - g0) < bpg ? (BATCH - g0) : bpg;
            dim3 grid(16, 16, gb);
            cost_kernel<<<grid, 256, 0, stream>>>(pred + (size_t)g0 * T_LEN * D_DIM,
                                                  targ + (size_t)g0 * T_LEN * D_DIM,
                                                  cost);
            dp_kernel<<<gb, 64, 0, stream>>>(cost, out);
        }
    } else {
        dp_fused_kernel<<<BATCH, 64, 0, stream>>>(pred, targ, out);
    }
}